// Round 1
// baseline (352.790 us; speedup 1.0000x reference)
//
#include <hip/hip_runtime.h>
#include <math.h>

// Problem constants (fixed by setup_inputs)
#define BB 2
#define CC 64
#define DD 64
#define HH 128
#define WW 128

#define DC 16                 // d-slab per block
#define HROWS 8               // h rows per block tile
#define NDCH (DD / DC)        // 4
#define NHT (HH / HROWS)      // 16
#define NPART (NDCH * NHT)    // 64 partials per (b,c)

// ---------------------------------------------------------------------------
// Kernel 1: streaming 19-tap Laplacian, per-block partial sum of |lap|.
// Stencil decomposition per slice:
//   S5(d)  = -6*c + (N+S+E+W)                      (outer kernel slices)
//   S9(d)  = 24*c - 6*(N+S+E+W) + diagonals        (mid kernel slice)
//   lap(d) = S9(d) + S5(d-1) + S5(d+1)             (zero pad outside volume)
// Each thread owns (h, w0..w0+3), slides a register window over d.
// ---------------------------------------------------------------------------
__global__ __launch_bounds__(256) void lap_score_partial(
    const float* __restrict__ x, float* __restrict__ partials) {
  const int bc  = blockIdx.x;   // 0..B*C-1
  const int dch = blockIdx.y;   // 0..NDCH-1
  const int ht  = blockIdx.z;   // 0..NHT-1
  const int tid = threadIdx.x;
  const int r   = tid >> 5;     // 0..7  (row within tile)
  const int wg  = tid & 31;     // 0..31 (float4 group)
  const int h   = ht * HROWS + r;
  const int w0  = wg * 4;
  const int d0  = dch * DC;

  const float* base = x + (size_t)bc * ((size_t)DD * HH * WW);

  // load row hh of slice sp into v[0..5] = {w0-1, w0..w0+3, w0+4}, zero-padded
  auto load_row = [&](const float* sp, int hh, float v[6]) {
    if (hh < 0 || hh >= HH) {
      v[0] = v[1] = v[2] = v[3] = v[4] = v[5] = 0.f;
      return;
    }
    const float* rp = sp + (size_t)hh * WW + w0;
    float4 c = *reinterpret_cast<const float4*>(rp);
    v[1] = c.x; v[2] = c.y; v[3] = c.z; v[4] = c.w;
    v[0] = (w0 > 0) ? rp[-1] : 0.f;
    v[5] = (w0 + 4 < WW) ? rp[4] : 0.f;
  };

  // compute S5 and S9 for slice d at this thread's 4 points
  auto slice_stencil = [&](int d, float s5[4], float s9[4]) {
    if (d < 0 || d >= DD) {
      for (int j = 0; j < 4; ++j) { s5[j] = 0.f; s9[j] = 0.f; }
      return;
    }
    const float* sp = base + (size_t)d * (HH * WW);
    float rm[6], rc[6], rp[6];
    load_row(sp, h - 1, rm);
    load_row(sp, h,     rc);
    load_row(sp, h + 1, rp);
#pragma unroll
    for (int j = 0; j < 4; ++j) {
      float cen = rc[j + 1];
      float A   = rm[j + 1] + rp[j + 1] + rc[j] + rc[j + 2];  // N+S+W+E
      float Dg  = rm[j] + rm[j + 2] + rp[j] + rp[j + 2];      // diagonals
      s5[j] = A - 6.f * cen;
      s9[j] = 24.f * cen - 6.f * A + Dg;
    }
  };

  float s5p[4], s5c[4], s9c[4], s5n[4], s9n[4], dum[4];
  slice_stencil(d0 - 1, s5p, dum);
  slice_stencil(d0,     s5c, s9c);

  float acc = 0.f;
  for (int d = d0; d < d0 + DC; ++d) {
    slice_stencil(d + 1, s5n, s9n);
#pragma unroll
    for (int j = 0; j < 4; ++j) acc += fabsf(s9c[j] + s5p[j] + s5n[j]);
#pragma unroll
    for (int j = 0; j < 4; ++j) { s5p[j] = s5c[j]; s5c[j] = s5n[j]; s9c[j] = s9n[j]; }
  }

  // deterministic block tree reduction
  __shared__ float red[256];
  red[tid] = acc;
  __syncthreads();
  for (int s = 128; s > 0; s >>= 1) {
    if (tid < s) red[tid] += red[tid + s];
    __syncthreads();
  }
  if (tid == 0) partials[(size_t)bc * NPART + dch * NHT + ht] = red[0];
}

// ---------------------------------------------------------------------------
// Kernel 2: deterministic serial reduce of NPART partials -> p[b*C+c]
// ---------------------------------------------------------------------------
__global__ void reduce_scores(const float* __restrict__ partials,
                              float* __restrict__ p) {
  int bc = blockIdx.x * blockDim.x + threadIdx.x;
  if (bc < BB * CC) {
    float s = 0.f;
    for (int i = 0; i < NPART; ++i) s += partials[bc * NPART + i];
    p[bc] = s;
  }
}

// ---------------------------------------------------------------------------
// Kernel 3: top-k by rank counting. Matches jax.lax.top_k semantics:
// descending values, ties broken by lower index first.
// ---------------------------------------------------------------------------
__global__ void topk_idx(const float* __restrict__ p, int* __restrict__ idx,
                         int k) {
  int b = blockIdx.x;
  int c = threadIdx.x;  // 0..C-1
  float v = p[b * CC + c];
  int rank = 0;
  for (int j = 0; j < CC; ++j) {
    float u = p[b * CC + j];
    rank += (u > v) || (u == v && j < c);
  }
  if (rank < k) idx[b * k + rank] = c;
}

// ---------------------------------------------------------------------------
// Kernel 4: gather selected channels (pure float4 copy).
// blockIdx.y = output slot (b*k + r); blocks in x grid-stride over the volume.
// ---------------------------------------------------------------------------
__global__ __launch_bounds__(256) void gather_channels(
    const float* __restrict__ x, const int* __restrict__ idx,
    float* __restrict__ out, int k) {
  const int slot = blockIdx.y;      // b*k + r
  const int b = slot / k;
  const long CH4 = (long)DD * HH * WW / 4;  // 262144 float4 per channel
  const int c = idx[slot];
  const float4* src = reinterpret_cast<const float4*>(x) + ((long)b * CC + c) * CH4;
  float4* dst = reinterpret_cast<float4*>(out) + (long)slot * CH4;
  for (long g = blockIdx.x * (long)blockDim.x + threadIdx.x; g < CH4;
       g += (long)gridDim.x * blockDim.x) {
    dst[g] = src[g];
  }
}

extern "C" void kernel_launch(void* const* d_in, const int* in_sizes, int n_in,
                              void* d_out, int out_size, void* d_ws,
                              size_t ws_size, hipStream_t stream) {
  const float* x = (const float*)d_in[0];
  float* out = (float*)d_out;

  // k derived host-side from out_size = B*k*D*H*W
  const int k = out_size / (BB * DD * HH * WW);  // = 32

  // workspace layout (all written before read every call; no zeroing needed)
  float* partials = (float*)d_ws;                    // B*C*NPART floats
  float* p        = partials + (size_t)BB * CC * NPART;  // B*C floats
  int*   idx      = (int*)(p + BB * CC);                 // B*k ints

  dim3 g1(BB * CC, NDCH, NHT);
  lap_score_partial<<<g1, 256, 0, stream>>>(x, partials);

  reduce_scores<<<1, 128, 0, stream>>>(partials, p);

  topk_idx<<<BB, CC, 0, stream>>>(p, idx, k);

  dim3 g4(64, BB * k);
  gather_channels<<<g4, 256, 0, stream>>>(x, idx, out, k);
}

// Round 2
// 270.766 us; speedup vs baseline: 1.3029x; 1.3029x over previous
//
#include <hip/hip_runtime.h>
#include <math.h>

// Problem constants (fixed by setup_inputs)
#define BB 2
#define CC 64
#define DD 64
#define HH 128
#define WW 128
#define HW (HH * WW)

#define DC 32                      // d-slab per block
#define NDCH (DD / DC)             // 2
#define RPT 2                      // consecutive rows per thread
#define ROWS_PER_BLOCK (8 * RPT)   // 16 (8 hr-groups)
#define NHT (HH / ROWS_PER_BLOCK)  // 8
#define NPART (NDCH * NHT)         // 16 partials per (b,c)

// ---------------------------------------------------------------------------
// Kernel 1: streaming 19-tap Laplacian, per-block partial sum of |lap|.
//   S5(d)  = -6*c + (N+S+E+W)                 (outer kernel slices)
//   S9(d)  = 24*c - 6*(N+S+E+W) + diagonals   (mid kernel slice)
//   lap(d) = S9(d) + S5(d-1) + S5(d+1)        (zero pad outside volume)
// Thread owns (h0..h0+1, w0..w0+3); slides a register window over d.
// Per slice it loads 4 rows (for 2 output rows), all loads issued up front.
// ---------------------------------------------------------------------------
__global__ __launch_bounds__(256) void lap_score_partial(
    const float* __restrict__ x, float* __restrict__ partials) {
  const int ht  = blockIdx.x;   // fastest: halo-sharing blocks co-resident
  const int dch = blockIdx.y;
  const int bc  = blockIdx.z;
  const int tid = threadIdx.x;
  const int hr  = tid >> 5;     // 0..7
  const int wg  = tid & 31;     // 0..31
  const int h0  = ht * ROWS_PER_BLOCK + hr * RPT;
  const int w0  = wg * 4;
  const int d0  = dch * DC;

  const float* colptr =
      x + (size_t)bc * ((size_t)DD * HW) + (size_t)h0 * WW + w0;
  const bool has_left  = (w0 > 0);
  const bool has_right = (w0 + 4 < WW);

  // load row h0+rr of the slice at sp into v[6] = {w0-1, w0..w0+3, w0+4}
  auto load_row = [&](const float* sp, int rr, float v[6]) {
    const int hh = h0 + rr;
    if (hh < 0 || hh >= HH) {
      v[0] = v[1] = v[2] = v[3] = v[4] = v[5] = 0.f;
      return;
    }
    const float* rp = sp + rr * WW;  // rr*WW folds into imm offsets
    float4 c4 = *reinterpret_cast<const float4*>(rp);
    v[1] = c4.x; v[2] = c4.y; v[3] = c4.z; v[4] = c4.w;
    v[0] = has_left ? rp[-1] : 0.f;
    v[5] = has_right ? rp[4] : 0.f;
  };

  // compute S5,S9 for this thread's RPT rows of slice d
  auto do_slice = [&](int d, float s5[RPT][4], float s9[RPT][4]) {
    if (d < 0 || d >= DD) {
#pragma unroll
      for (int i = 0; i < RPT; ++i)
#pragma unroll
        for (int j = 0; j < 4; ++j) { s5[i][j] = 0.f; s9[i][j] = 0.f; }
      return;
    }
    const float* sp = colptr + (size_t)d * HW;
    float v[RPT + 2][6];
#pragma unroll
    for (int rr = 0; rr < RPT + 2; ++rr) load_row(sp, rr - 1, v[rr]);
    float hs[RPT + 2][4];  // horizontal pair sums per loaded row
#pragma unroll
    for (int rr = 0; rr < RPT + 2; ++rr)
#pragma unroll
      for (int j = 0; j < 4; ++j) hs[rr][j] = v[rr][j] + v[rr][j + 2];
#pragma unroll
    for (int i = 0; i < RPT; ++i) {
#pragma unroll
      for (int j = 0; j < 4; ++j) {
        float cen = v[i + 1][j + 1];
        float t = hs[i + 1][j] + v[i][j + 1] + v[i + 2][j + 1];  // N+S+E+W
        s5[i][j] = fmaf(-6.f, cen, t);
        s9[i][j] = fmaf(24.f, cen, fmaf(-6.f, t, hs[i][j] + hs[i + 2][j]));
      }
    }
  };

  float s5p[RPT][4], s5c[RPT][4], s9c[RPT][4], s5n[RPT][4], s9n[RPT][4],
      dum[RPT][4];
  do_slice(d0 - 1, s5p, dum);
  do_slice(d0, s5c, s9c);

  float acc = 0.f;
  for (int d = d0; d < d0 + DC; ++d) {
    do_slice(d + 1, s5n, s9n);
#pragma unroll
    for (int i = 0; i < RPT; ++i)
#pragma unroll
      for (int j = 0; j < 4; ++j) {
        acc += fabsf(s9c[i][j] + s5p[i][j] + s5n[i][j]);
        s5p[i][j] = s5c[i][j];
        s5c[i][j] = s5n[i][j];
        s9c[i][j] = s9n[i][j];
      }
  }

  // deterministic block tree reduction
  __shared__ float red[256];
  red[tid] = acc;
  __syncthreads();
  for (int s = 128; s > 0; s >>= 1) {
    if (tid < s) red[tid] += red[tid + s];
    __syncthreads();
  }
  if (tid == 0) partials[(size_t)bc * NPART + dch * NHT + ht] = red[0];
}

// ---------------------------------------------------------------------------
// Kernel 2: fused score-reduce + top-k rank selection.
// Matches jax.lax.top_k semantics: descending, ties -> lower index first.
// ---------------------------------------------------------------------------
__global__ void score_topk(const float* __restrict__ partials,
                           int* __restrict__ idx, int k) {
  const int b = blockIdx.x;
  const int c = threadIdx.x;  // 0..C-1
  const float* pp = partials + (size_t)(b * CC + c) * NPART;
  float s = 0.f;
#pragma unroll
  for (int i = 0; i < NPART; ++i) s += pp[i];  // fixed serial order
  __shared__ float sm[CC];
  sm[c] = s;
  __syncthreads();
  int rank = 0;
  for (int j = 0; j < CC; ++j) {
    float u = sm[j];
    rank += (u > s) || (u == s && j < c);
  }
  if (rank < k) idx[b * k + rank] = c;
}

// ---------------------------------------------------------------------------
// Kernel 3: gather selected channels (pure float4 copy).
// ---------------------------------------------------------------------------
__global__ __launch_bounds__(256) void gather_channels(
    const float* __restrict__ x, const int* __restrict__ idx,
    float* __restrict__ out, int k) {
  const int slot = blockIdx.y;  // b*k + r
  const int b = slot / k;
  const long CH4 = (long)DD * HW / 4;  // 262144 float4 per channel
  const int c = idx[slot];
  const float4* src =
      reinterpret_cast<const float4*>(x) + ((long)b * CC + c) * CH4;
  float4* dst = reinterpret_cast<float4*>(out) + (long)slot * CH4;
  for (long g = blockIdx.x * (long)blockDim.x + threadIdx.x; g < CH4;
       g += (long)gridDim.x * blockDim.x) {
    dst[g] = src[g];
  }
}

extern "C" void kernel_launch(void* const* d_in, const int* in_sizes, int n_in,
                              void* d_out, int out_size, void* d_ws,
                              size_t ws_size, hipStream_t stream) {
  const float* x = (const float*)d_in[0];
  float* out = (float*)d_out;

  const int k = out_size / (BB * DD * HH * WW);  // = 32

  // workspace layout (fully written before read every call)
  float* partials = (float*)d_ws;                        // B*C*NPART floats
  int* idx = (int*)(partials + (size_t)BB * CC * NPART); // B*k ints

  dim3 g1(NHT, NDCH, BB * CC);  // ht fastest: halo-sharing blocks co-resident
  lap_score_partial<<<g1, 256, 0, stream>>>(x, partials);

  score_topk<<<BB, CC, 0, stream>>>(partials, idx, k);

  dim3 g3(128, BB * k);
  gather_channels<<<g3, 256, 0, stream>>>(x, idx, out, k);
}